// Round 12
// baseline (358.332 us; speedup 1.0000x reference)
//
#include <hip/hip_runtime.h>
#include <hip/hip_bf16.h>
#include <stdint.h>

#define B_ 8
#define T_ 1024
#define E_ 1024
#define H_ 16
#define D_ 64
#define NREL 2047  // 2T-1

using bf16 = __hip_bfloat16;
typedef __attribute__((ext_vector_type(8))) short bhalf8;   // 8 bf16 = 4 VGPRs
typedef __attribute__((ext_vector_type(4))) float f32x4;

// --- async global->LDS, 16B/lane. LDS dest = wave-uniform base + lane*16. ---
typedef __attribute__((address_space(3))) uint32_t lds32_t;
typedef const __attribute__((address_space(1))) uint32_t glb32_t;
__device__ __forceinline__ void gld_lds16(const void* g, void* l) {
  __builtin_amdgcn_global_load_lds((glb32_t*)g, (lds32_t*)l, 16, 0, 0);
}

__device__ __forceinline__ bhalf8 cvt8(const float4 a, const float4 b) {
  bf16 t[8];
  t[0] = __float2bfloat16(a.x); t[1] = __float2bfloat16(a.y);
  t[2] = __float2bfloat16(a.z); t[3] = __float2bfloat16(a.w);
  t[4] = __float2bfloat16(b.x); t[5] = __float2bfloat16(b.y);
  t[6] = __float2bfloat16(b.z); t[7] = __float2bfloat16(b.w);
  return *(const bhalf8*)t;
}

// ---------------------------------------------------------------------------
// fp32->bf16 for the four weights (z=0..3) + temporal-bias precompute (z=4)
// in one dispatch. Bias pre-scaled by log2(e).
// ---------------------------------------------------------------------------
__global__ __launch_bounds__(256) void cvt_w4b(const float* __restrict__ Wq,
                                               const float* __restrict__ Wk,
                                               const float* __restrict__ Wv,
                                               const float* __restrict__ Wo,
                                               bf16* __restrict__ d,
                                               const float* __restrict__ table,
                                               const float* __restrict__ offset,
                                               float* __restrict__ db) {
  const int z = blockIdx.y;
  if (z == 4) {
    const int idx = blockIdx.x * 256 + threadIdx.x;
    if (idx >= NREL * H_) return;
    const int r = idx >> 4;
    const int h = idx & 15;
    const float bounded = tanhf(offset[0]) * 0.5f;
    float adj = (float)r + bounded;
    adj = fminf(fmaxf(adj, 0.f), 2046.f);
    const int lo = (int)floorf(adj);
    const int hi = (int)ceilf(adj);
    const float wgt = adj - (float)lo;
    const float v = table[lo * H_ + h] * (1.f - wgt) + table[hi * H_ + h] * wgt;
    db[h * NREL + r] = v * 1.4426950408889634f;  // fold log2(e)
    return;
  }
  const float* s = (z == 0) ? Wq : (z == 1) ? Wk : (z == 2) ? Wv : Wo;
  const int i = (blockIdx.x * 256 + threadIdx.x) * 8;
  const float4 a = *(const float4*)(s + i);
  const float4 b = *(const float4*)(s + i + 4);
  *(bhalf8*)(d + (size_t)z * E_ * E_ + i) = cvt8(a, b);
}

// ---------------------------------------------------------------------------
// Fused QKV projection, grid (64,8,3), 128x128 tile. (R11 form, 113 us --
// structural floor: 7 schedule variants R4-R11 bracket 113-148.)
// A staged as RAW F32 via global_load_lds; f32->bf16 at fragment-load time.
// T2/rule-21 swizzle on the f32 A tile (linear LDS dest + inverse-swizzled
// global source + same XOR on read). LDS 48 KB -> 3 blocks/CU.
// ---------------------------------------------------------------------------
__global__ __launch_bounds__(256, 3) void gemm_qkv(const float* __restrict__ Xq,
                                                   const float* __restrict__ Xk,
                                                   const float* __restrict__ Xv,
                                                   const bf16* __restrict__ Wc,
                                                   const float* __restrict__ bqp,
                                                   const float* __restrict__ bkp,
                                                   const float* __restrict__ bvp,
                                                   bf16* __restrict__ dst) {
  __shared__ float AsF[2 * 128 * 32];   // 32 KB, f32 A tiles (swizzled cols)
  __shared__ bf16 Bs[2 * 128 * 32];     // 16 KB
  const int tid = threadIdx.x;
  const int lane = tid & 63;
  const int w = tid >> 6;
  const int quad = lane >> 4;
  const int l15 = lane & 15;
  const int m0 = blockIdx.x * 128;
  const int n0 = blockIdx.y * 128;
  const int z = blockIdx.z;
  const float* A = (z == 0) ? Xq : ((z == 1) ? Xk : Xv);
  const float* bias = (z == 0) ? bqp : ((z == 1) ? bkp : bvp);
  const bf16* W = Wc + (size_t)z * E_ * E_;
  bf16* out = dst + (size_t)z * B_ * T_ * D_ * H_;
  const int wm = (w >> 1) * 64;
  const int wn = (w & 1) * 64;

  const f32x4 zero4 = {0.f, 0.f, 0.f, 0.f};
  f32x4 acc[4][4];
#pragma unroll
  for (int i = 0; i < 4; ++i)
#pragma unroll
    for (int j = 0; j < 4; ++j) acc[i][j] = zero4;

  const int g = tid;
  const int arow = g >> 3;                       // 0..31 (chunk c adds c*32)
  const int acol = (((g & 7) ^ ((g >> 3) & 7)) << 2);
  const float* Ag = A + (size_t)(m0 + arow) * E_ + acol;
  float* AsDst = AsF + g * 4;                    // + buf*4096 + c*1024 (f32)
  const int srowW = w * 32 + (lane >> 2);
  const int scolW = (lane & 3) * 8;
  const bf16* Wg = W + (size_t)(n0 + srowW) * E_ + scolW;
  bf16* BsDst = Bs + w * 1024 + lane * 8;        // + buf*4096 (bf16)

  // prologue: stage kt=0 into buf0
#pragma unroll
  for (int c = 0; c < 4; ++c)
    gld_lds16(Ag + (size_t)c * 32 * E_, AsDst + c * 1024);
  gld_lds16(Wg, BsDst);
  gld_lds16(Wg + (size_t)16 * E_, BsDst + 512);
  __syncthreads();

  for (int kt = 0; kt < 32; ++kt) {
    const int curA = (kt & 1) * 4096;   // f32 elems
    const int curB = (kt & 1) * 4096;   // bf16 elems
    bhalf8 af[4], bfr[4];
#pragma unroll
    for (int mt = 0; mt < 4; ++mt) {
      const int row = wm + mt * 16 + l15;
      const int cb = (quad * 32) ^ ((row & 7) << 4);   // byte offset in row
      const char* rp = (const char*)(AsF + curA + row * 32);
      const float4 lo = *(const float4*)(rp + cb);
      const float4 hi = *(const float4*)(rp + (cb ^ 16));
      af[mt] = cvt8(lo, hi);
    }
#pragma unroll
    for (int nt = 0; nt < 4; ++nt)
      bfr[nt] = *(const bhalf8*)(Bs + curB + (wn + nt * 16 + l15) * 32 + quad * 8);
    if (kt < 31) {
      const int nxtA = 4096 - curA;
      const int nxtB = 4096 - curB;
      const int kc = (kt + 1) * 32;
#pragma unroll
      for (int c = 0; c < 4; ++c)
        gld_lds16(Ag + (size_t)c * 32 * E_ + kc, AsDst + nxtA + c * 1024);
      gld_lds16(Wg + kc, BsDst + nxtB);
      gld_lds16(Wg + (size_t)16 * E_ + kc, BsDst + nxtB + 512);
    }
#pragma unroll
    for (int mt = 0; mt < 4; ++mt)
#pragma unroll
      for (int nt = 0; nt < 4; ++nt)
        acc[mt][nt] = __builtin_amdgcn_mfma_f32_16x16x32_bf16(af[mt], bfr[nt], acc[mt][nt], 0, 0, 0);
    __syncthreads();
  }

#pragma unroll
  for (int mt = 0; mt < 4; ++mt) {
#pragma unroll
    for (int nt = 0; nt < 4; ++nt) {
      const int n = n0 + wn + nt * 16 + l15;
      const float bv = bias[n];
#pragma unroll
      for (int r = 0; r < 4; ++r) {
        const int m = m0 + wm + mt * 16 + quad * 4 + r;  // C row = quad*4+reg
        const float v = acc[mt][nt][r] + bv;
        const int bb = m >> 10, tq = m & 1023, hh = n >> 6, d = n & 63;
        out[(((size_t)bb * H_ + hh) * T_ + tq) * D_ + d] = __float2bfloat16(v);
      }
    }
  }
}

// ---------------------------------------------------------------------------
// Output projection (reverted to the R5-proven 128x128 form: the R9 64x128
// change was a ~5 us regression -- R5 total 346.8 vs R11 352.2 with all
// other kernels perf-identical). dbuf, single barrier, both via gld_lds.
// ---------------------------------------------------------------------------
template <int SCATTER, int F32OUT>
__global__ __launch_bounds__(256) void gemm_bt(const bf16* __restrict__ A,
                                               const bf16* __restrict__ W,
                                               const float* __restrict__ bias,
                                               void* __restrict__ dst_) {
  __shared__ bf16 As[2 * 128 * 32];
  __shared__ bf16 Bs[2 * 128 * 32];
  const int tid = threadIdx.x;
  const int lane = tid & 63;
  const int w = tid >> 6;
  const int quad = lane >> 4;
  const int l15 = lane & 15;
  const int m0 = blockIdx.x * 128;
  const int n0 = blockIdx.y * 128;
  const int wm = (w >> 1) * 64;
  const int wn = (w & 1) * 64;

  const f32x4 zero4 = {0.f, 0.f, 0.f, 0.f};
  f32x4 acc[4][4];
#pragma unroll
  for (int i = 0; i < 4; ++i)
#pragma unroll
    for (int j = 0; j < 4; ++j) acc[i][j] = zero4;

  const int srow0 = w * 32 + (lane >> 2);
  const int scol = (lane & 3) * 8;
  const bf16* Ag = A + (size_t)(m0 + srow0) * E_ + scol;
  const bf16* Wg = W + (size_t)(n0 + srow0) * E_ + scol;
  const int sidx = w * 1024 + lane * 8;

  gld_lds16(Ag, As + sidx);
  gld_lds16(Ag + (size_t)16 * E_, As + sidx + 512);
  gld_lds16(Wg, Bs + sidx);
  gld_lds16(Wg + (size_t)16 * E_, Bs + sidx + 512);
  __syncthreads();

  for (int kt = 0; kt < 32; ++kt) {
    const int cur = (kt & 1) * 4096;
    bhalf8 af[4], bfr[4];
#pragma unroll
    for (int t = 0; t < 4; ++t) {
      af[t] = *(const bhalf8*)(As + cur + (wm + t * 16 + l15) * 32 + quad * 8);
      bfr[t] = *(const bhalf8*)(Bs + cur + (wn + t * 16 + l15) * 32 + quad * 8);
    }
    if (kt < 31) {
      const int nxt = 4096 - cur;
      const int kc = (kt + 1) * 32;
      gld_lds16(Ag + kc, As + nxt + sidx);
      gld_lds16(Ag + (size_t)16 * E_ + kc, As + nxt + sidx + 512);
      gld_lds16(Wg + kc, Bs + nxt + sidx);
      gld_lds16(Wg + (size_t)16 * E_ + kc, Bs + nxt + sidx + 512);
    }
#pragma unroll
    for (int mt = 0; mt < 4; ++mt)
#pragma unroll
      for (int nt = 0; nt < 4; ++nt)
        acc[mt][nt] = __builtin_amdgcn_mfma_f32_16x16x32_bf16(af[mt], bfr[nt], acc[mt][nt], 0, 0, 0);
    __syncthreads();
  }

#pragma unroll
  for (int mt = 0; mt < 4; ++mt) {
#pragma unroll
    for (int nt = 0; nt < 4; ++nt) {
      const int n = n0 + wn + nt * 16 + l15;
      const float bv = bias[n];
#pragma unroll
      for (int r = 0; r < 4; ++r) {
        const int m = m0 + wm + mt * 16 + quad * 4 + r;  // C row = quad*4+reg
        const float v = acc[mt][nt][r] + bv;
        if (SCATTER) {
          const int bb = m >> 10, t = m & 1023, hh = n >> 6, d = n & 63;
          ((bf16*)dst_)[(((size_t)bb * H_ + hh) * T_ + t) * D_ + d] = __float2bfloat16(v);
        } else if (F32OUT) {
          ((float*)dst_)[(size_t)m * E_ + n] = v;
        } else {
          ((bf16*)dst_)[(size_t)m * E_ + n] = __float2bfloat16(v);
        }
      }
    }
  }
}

// ---------------------------------------------------------------------------
// Flash attention, swapped-operand structure. R12 changes vs the R2 form:
//  (1) PAIRED V staging: two V tiles (Vt[2]) staged per barrier pair ->
//      barrier regions halved (16 -> 8); the second inner iteration runs
//      with no barrier. WAR-safe: next pair's Vt writes follow the barrier
//      that follows all this pair's PV reads; Ps is wave-private.
//  (2) XCD-locality 1-D grid: n = qt*128 + bh -> XCD(n%8) = bh%8, so all
//      8 q-tile blocks sharing one 256KB K/V panel land on ONE XCD ->
//      K-frag + V-prefetch loads become L2 hits instead of L3 (T1).
// LDS: Vt 2*9216 + Ps 16384 + dbs 4608 = 39424 B -> 4 blocks/CU.
// ---------------------------------------------------------------------------
__device__ __forceinline__ int ps_off(int row, int colbyte) {
  return row * 128 + (colbyte ^ ((row & 7) << 4));
}

__global__ __launch_bounds__(256, 4) void attn_kernel(const bf16* __restrict__ Q,
                                                      const bf16* __restrict__ K,
                                                      const bf16* __restrict__ V,
                                                      const float* __restrict__ db,
                                                      bf16* __restrict__ xout) {
  const int tid = threadIdx.x;
  const int lane = tid & 63;
  const int w = tid >> 6;
  const int quad = lane >> 4;
  const int l15 = lane & 15;
  const int n = blockIdx.x;
  const int bh = n & 127;             // b*16 + h  (fast axis -> XCD = bh%8)
  const int h = bh & 15;
  const int b = bh >> 4;
  const int q0 = (n >> 7) * 128;

  __shared__ bf16 Vt[2][64][72];                 // rotated V^T, pair-staged
  __shared__ __align__(16) bf16 Ps[4][32 * 64];  // swizzled P / O tiles (16384 B)
  __shared__ float dbs[1152];                    // bias slice (4608 B)

  const size_t base = (size_t)bh * T_ * D_;
  const bf16* Qp = Q + base;
  const bf16* Kp = K + base;
  const bf16* Vp = V + base;
  const float* dbh = db + h * NREL;

  for (int t = tid; t < 1151; t += 256) dbs[t] = dbh[q0 + t];

  const int qw = q0 + w * 32;
  bhalf8 aq[2][2];
#pragma unroll
  for (int mt = 0; mt < 2; ++mt)
#pragma unroll
    for (int ks = 0; ks < 2; ++ks)
      aq[mt][ks] = *(const bhalf8*)(Qp + (size_t)(qw + mt * 16 + l15) * D_ + ks * 32 + quad * 8);

  const f32x4 zero4 = {0.f, 0.f, 0.f, 0.f};
  f32x4 o[2][4];
#pragma unroll
  for (int mt = 0; mt < 2; ++mt)
#pragma unroll
    for (int nt = 0; nt < 4; ++nt) o[mt][nt] = zero4;
  float mrow[2] = {-1e30f, -1e30f};   // log2 units
  float lrow[2] = {0.f, 0.f};

  // V staging: 4 chunks/thread per PAIR (tiles 2pt, 2pt+1)
  const int vrow0 = tid >> 3;              // kv local 0..31
  const int vc8 = (tid & 7) * 8;           // d chunk
  bhalf8 vreg[4];
  vreg[0] = *(const bhalf8*)(Vp + (size_t)vrow0 * D_ + vc8);
  vreg[1] = *(const bhalf8*)(Vp + (size_t)(vrow0 + 32) * D_ + vc8);
  vreg[2] = *(const bhalf8*)(Vp + (size_t)(64 + vrow0) * D_ + vc8);
  vreg[3] = *(const bhalf8*)(Vp + (size_t)(64 + vrow0 + 32) * D_ + vc8);

  char* const psw = (char*)&Ps[w][0];
  const int rot = (l15 >> 3);

  for (int pt = 0; pt < 8; ++pt) {
    const int kb0 = pt * 128;
    // K frags for inner iteration A -- issue before the barrier region
    bhalf8 bk[4][2];
#pragma unroll
    for (int nt = 0; nt < 4; ++nt) {
      const bf16* kr = Kp + (size_t)(kb0 + nt * 16 + l15) * D_ + quad * 8;
      bk[nt][0] = *(const bhalf8*)kr;
      bk[nt][1] = *(const bhalf8*)(kr + 32);
    }

    __syncthreads();                  // previous pair's Vt readers done
    // write both prefetched V tiles -> rotated Vt[0], Vt[1]
#pragma unroll
    for (int s = 0; s < 4; ++s) {
      const int row = vrow0 + (s & 1) * 32;
      const bf16* vp = (const bf16*)&vreg[s];
      const int kvp = (row + vc8) & 63;      // rotation: kv + (d&56)
#pragma unroll
      for (int j = 0; j < 8; ++j) Vt[s >> 1][vc8 + j][kvp] = vp[j];
    }
    __syncthreads();
    // prefetch next pair's V tiles (hidden under 2 full compute iterations)
    if (pt < 7) {
      const int kb2 = kb0 + 128;
      vreg[0] = *(const bhalf8*)(Vp + (size_t)(kb2 + vrow0) * D_ + vc8);
      vreg[1] = *(const bhalf8*)(Vp + (size_t)(kb2 + vrow0 + 32) * D_ + vc8);
      vreg[2] = *(const bhalf8*)(Vp + (size_t)(kb2 + 64 + vrow0) * D_ + vc8);
      vreg[3] = *(const bhalf8*)(Vp + (size_t)(kb2 + 64 + vrow0 + 32) * D_ + vc8);
    }

#pragma unroll
    for (int half = 0; half < 2; ++half) {
      const int kb = kb0 + half * 64;
      // K frags for inner iteration B (loaded after A's S-MFMAs consumed bk)
      if (half == 1) {
#pragma unroll
        for (int nt = 0; nt < 4; ++nt) {
          const bf16* kr = Kp + (size_t)(kb + nt * 16 + l15) * D_ + quad * 8;
          bk[nt][0] = *(const bhalf8*)kr;
          bk[nt][1] = *(const bhalf8*)(kr + 32);
        }
      }

      // S^T = K Q^T
      f32x4 s4[2][4];
      __builtin_amdgcn_s_setprio(1);
#pragma unroll
      for (int nt = 0; nt < 4; ++nt) {
#pragma unroll
        for (int mt = 0; mt < 2; ++mt) {
          f32x4 a = zero4;
          a = __builtin_amdgcn_mfma_f32_16x16x32_bf16(bk[nt][0], aq[mt][0], a, 0, 0, 0);
          a = __builtin_amdgcn_mfma_f32_16x16x32_bf16(bk[nt][1], aq[mt][1], a, 0, 0, 0);
          s4[mt][nt] = a;
        }
      }
      __builtin_amdgcn_s_setprio(0);

      // softmax over kv (log2 domain): scale*log2e folded, bias pre-scaled
#pragma unroll
      for (int mt = 0; mt < 2; ++mt) {
        const int ib = w * 32 + mt * 16 + l15 + 1023 - kb;
        float mnt[4];
#pragma unroll
        for (int nt = 0; nt < 4; ++nt) {
#pragma unroll
          for (int r = 0; r < 4; ++r) {
            const float sv = s4[mt][nt][r] * 0.18033688011112042f + dbs[ib - nt * 16 - quad * 4 - r];
            s4[mt][nt][r] = sv;
          }
          mnt[nt] = fmaxf(fmaxf(s4[mt][nt][0], s4[mt][nt][1]),
                          fmaxf(s4[mt][nt][2], s4[mt][nt][3]));
        }
        float tmx = fmaxf(fmaxf(mnt[0], mnt[1]), fmaxf(mnt[2], mnt[3]));
        tmx = fmaxf(tmx, __shfl_xor(tmx, 16, 64));
        tmx = fmaxf(tmx, __shfl_xor(tmx, 32, 64));
        // defer-max (T13): 8 e-units ~= 11.5 log2-units
        if (!__all(tmx - mrow[mt] <= 11.0f)) {
          const float mnew = fmaxf(mrow[mt], tmx);
          const float alpha = __builtin_amdgcn_exp2f(mrow[mt] - mnew);
          mrow[mt] = mnew;
          lrow[mt] *= alpha;
#pragma unroll
          for (int nt = 0; nt < 4; ++nt) o[mt][nt] *= alpha;
        }
        const float mcur = mrow[mt];
        float psum[4];
#pragma unroll
        for (int nt = 0; nt < 4; ++nt) {
          float p0 = __builtin_amdgcn_exp2f(s4[mt][nt][0] - mcur);
          float p1 = __builtin_amdgcn_exp2f(s4[mt][nt][1] - mcur);
          float p2 = __builtin_amdgcn_exp2f(s4[mt][nt][2] - mcur);
          float p3 = __builtin_amdgcn_exp2f(s4[mt][nt][3] - mcur);
          s4[mt][nt][0] = p0; s4[mt][nt][1] = p1;
          s4[mt][nt][2] = p2; s4[mt][nt][3] = p3;
          psum[nt] = (p0 + p1) + (p2 + p3);
        }
        float sum = (psum[0] + psum[1]) + (psum[2] + psum[3]);
        sum += __shfl_xor(sum, 16, 64);
        sum += __shfl_xor(sum, 32, 64);
        lrow[mt] += sum;

        // P -> LDS (swizzled, wave-private -> no barrier needed)
#pragma unroll
        for (int nt = 0; nt < 4; ++nt) {
          alignas(8) bf16 t4[4];
#pragma unroll
          for (int r = 0; r < 4; ++r) t4[r] = __float2bfloat16(s4[mt][nt][r]);
          *(uint2*)(psw + ps_off(mt * 16 + l15, nt * 32 + quad * 8)) = *(const uint2*)t4;
        }
      }

      // PV: P B-frags (swizzled) + rotated-V^T A-frags -> O^T += V^T @ P
      bhalf8 pb[2][2];
#pragma unroll
      for (int mt = 0; mt < 2; ++mt)
#pragma unroll
        for (int ks = 0; ks < 2; ++ks)
          pb[mt][ks] = *(const bhalf8*)(psw + ps_off(mt * 16 + l15, ks * 64 + quad * 16));
      __builtin_amdgcn_s_setprio(1);
#pragma unroll
      for (int nt = 0; nt < 4; ++nt) {
        const int drow = nt * 16 + l15;
#pragma unroll
        for (int ks = 0; ks < 2; ++ks) {
          const int gp = (4 * ks + quad + 2 * nt + rot) & 7;
          const bhalf8 vb = *(const bhalf8*)&Vt[half][drow][gp * 8];
#pragma unroll
          for (int mt = 0; mt < 2; ++mt)
            o[mt][nt] = __builtin_amdgcn_mfma_f32_16x16x32_bf16(vb, pb[mt][ks], o[mt][nt], 0, 0, 0);
        }
      }
      __builtin_amdgcn_s_setprio(0);
    }
  }

  // epilogue: O^T/l -> Ps (wave-private, swizzled) -> coalesced b128 stores
#pragma unroll
  for (int mt = 0; mt < 2; ++mt) {
    const float inv = 1.f / lrow[mt];
#pragma unroll
    for (int nt = 0; nt < 4; ++nt) {
      alignas(8) bf16 t4[4];
#pragma unroll
      for (int r = 0; r < 4; ++r) t4[r] = __float2bfloat16(o[mt][nt][r] * inv);
      *(uint2*)(psw + ps_off(mt * 16 + l15, nt * 32 + quad * 8)) = *(const uint2*)t4;
    }
  }
#pragma unroll
  for (int t = 0; t < 4; ++t) {
    const int idx = t * 64 + lane;     // 256 16B chunks: 32 rows x 8 chunks
    const int row = idx >> 3;
    const int c = idx & 7;
    const bhalf8 val = *(const bhalf8*)(psw + ps_off(row, c * 16));
    *(bhalf8*)&xout[((size_t)b * T_ + qw + row) * E_ + h * D_ + c * 8] = val;
  }
}

// ---------------------------------------------------------------------------
extern "C" void kernel_launch(void* const* d_in, const int* in_sizes, int n_in,
                              void* d_out, int out_size, void* d_ws, size_t ws_size,
                              hipStream_t stream) {
  const float* query = (const float*)d_in[0];
  const float* key_  = (const float*)d_in[1];
  const float* value = (const float*)d_in[2];
  const float* Wq = (const float*)d_in[3];
  const float* bq = (const float*)d_in[4];
  const float* Wk = (const float*)d_in[5];
  const float* bk = (const float*)d_in[6];
  const float* Wv = (const float*)d_in[7];
  const float* bv = (const float*)d_in[8];
  const float* Wo = (const float*)d_in[9];
  const float* bo = (const float*)d_in[10];
  const float* table = (const float*)d_in[11];
  const float* offset = (const float*)d_in[12];
  float* out = (float*)d_out;

  char* ws = (char*)d_ws;
  const size_t ME = (size_t)B_ * T_ * E_;   // 8.4M elems
  const size_t EE = (size_t)E_ * E_;        // 1M elems
  float* db = (float*)ws;                   // 131008 B, round to 131072
  bf16* wc  = (bf16*)(ws + 131072);         // converted Wq,Wk,Wv,Wo (4*EE)
  bf16* qb  = wc + 4 * EE;                  // fused QKV out: [3][B,H,T,D]
  bf16* kb  = qb + ME;
  bf16* vb2 = kb + ME;
  bf16* x2  = vb2 + ME;                     // attn out [B,T,E]

  dim3 bb(256, 1, 1);
  const int gEE = (int)(EE / 8 / 256);

  // weights cvt (z=0..3) + bias table precompute (z=4), one dispatch
  cvt_w4b<<<dim3(gEE, 5), bb, 0, stream>>>(Wq, Wk, Wv, Wo, wc, table, offset, db);

  // fused QKV: f32-A via global_load_lds (swizzled), dbuf single barrier
  gemm_qkv<<<dim3(64, 8, 3), bb, 0, stream>>>(query, key_, value, wc, bq, bk, bv, qb);

  // attn: 1-D grid, bh-fastest (XCD locality for K/V panels)
  attn_kernel<<<dim3(1024), bb, 0, stream>>>(qb, kb, vb2, db, x2);

  gemm_bt<0, 1><<<dim3(64, 8, 1), bb, 0, stream>>>(x2, wc + 3 * EE, bo, out);
}

// Round 14
// 343.262 us; speedup vs baseline: 1.0439x; 1.0439x over previous
//
#include <hip/hip_runtime.h>
#include <hip/hip_bf16.h>
#include <stdint.h>

#define B_ 8
#define T_ 1024
#define E_ 1024
#define H_ 16
#define D_ 64
#define NREL 2047  // 2T-1

using bf16 = __hip_bfloat16;
typedef __attribute__((ext_vector_type(8))) short bhalf8;   // 8 bf16 = 4 VGPRs
typedef __attribute__((ext_vector_type(4))) float f32x4;

// --- async global->LDS, 16B/lane. LDS dest = wave-uniform base + lane*16. ---
typedef __attribute__((address_space(3))) uint32_t lds32_t;
typedef const __attribute__((address_space(1))) uint32_t glb32_t;
__device__ __forceinline__ void gld_lds16(const void* g, void* l) {
  __builtin_amdgcn_global_load_lds((glb32_t*)g, (lds32_t*)l, 16, 0, 0);
}

__device__ __forceinline__ bhalf8 cvt8(const float4 a, const float4 b) {
  bf16 t[8];
  t[0] = __float2bfloat16(a.x); t[1] = __float2bfloat16(a.y);
  t[2] = __float2bfloat16(a.z); t[3] = __float2bfloat16(a.w);
  t[4] = __float2bfloat16(b.x); t[5] = __float2bfloat16(b.y);
  t[6] = __float2bfloat16(b.z); t[7] = __float2bfloat16(b.w);
  return *(const bhalf8*)t;
}

// ---------------------------------------------------------------------------
// fp32->bf16 for the four weights (z=0..3) + temporal-bias precompute (z=4)
// in one dispatch. Bias pre-scaled by log2(e).
// ---------------------------------------------------------------------------
__global__ __launch_bounds__(256) void cvt_w4b(const float* __restrict__ Wq,
                                               const float* __restrict__ Wk,
                                               const float* __restrict__ Wv,
                                               const float* __restrict__ Wo,
                                               bf16* __restrict__ d,
                                               const float* __restrict__ table,
                                               const float* __restrict__ offset,
                                               float* __restrict__ db) {
  const int z = blockIdx.y;
  if (z == 4) {
    const int idx = blockIdx.x * 256 + threadIdx.x;
    if (idx >= NREL * H_) return;
    const int r = idx >> 4;
    const int h = idx & 15;
    const float bounded = tanhf(offset[0]) * 0.5f;
    float adj = (float)r + bounded;
    adj = fminf(fmaxf(adj, 0.f), 2046.f);
    const int lo = (int)floorf(adj);
    const int hi = (int)ceilf(adj);
    const float wgt = adj - (float)lo;
    const float v = table[lo * H_ + h] * (1.f - wgt) + table[hi * H_ + h] * wgt;
    db[h * NREL + r] = v * 1.4426950408889634f;  // fold log2(e)
    return;
  }
  const float* s = (z == 0) ? Wq : (z == 1) ? Wk : (z == 2) ? Wv : Wo;
  const int i = (blockIdx.x * 256 + threadIdx.x) * 8;
  const float4 a = *(const float4*)(s + i);
  const float4 b = *(const float4*)(s + i + 4);
  *(bhalf8*)(d + (size_t)z * E_ * E_ + i) = cvt8(a, b);
}

// ---------------------------------------------------------------------------
// Fused QKV projection, grid (64,8,3), 128x128 tile. R5 form -- the fastest
// of 8 measured schedule variants (113 us; counted-vmcnt, f32-gld_lds,
// swizzles, 8-wave, BN64, L2-swizzle all null or worse). LDS dbuf, single
// barrier per K-step; A reg-staged from f32 with inline cvt + 1-iter reg
// prefetch; W via gld_lds width-16.
// NOTE (R13 lesson): the 6.3M SQ_LDS_BANK_CONFLICT here is footprint-
// determined -- each frag-read instruction touches 16 rows x 64B-stride =
// only 8 of 32 bank groups; no lane-permutation/XOR can change the address
// SET per instruction. A fix needs row-pad geometry, which gld_lds forbids.
// Recoverable cost ~1k cy/block -> not worth the geometry rewrite.
// LDS 32 KB -> 3 blocks/CU.
// ---------------------------------------------------------------------------
__global__ __launch_bounds__(256, 3) void gemm_qkv(const float* __restrict__ Xq,
                                                   const float* __restrict__ Xk,
                                                   const float* __restrict__ Xv,
                                                   const bf16* __restrict__ Wc,
                                                   const float* __restrict__ bqp,
                                                   const float* __restrict__ bkp,
                                                   const float* __restrict__ bvp,
                                                   bf16* __restrict__ dst) {
  __shared__ bf16 As[2 * 128 * 32];
  __shared__ bf16 Bs[2 * 128 * 32];
  const int tid = threadIdx.x;
  const int lane = tid & 63;
  const int w = tid >> 6;
  const int quad = lane >> 4;
  const int l15 = lane & 15;
  const int m0 = blockIdx.x * 128;
  const int n0 = blockIdx.y * 128;
  const int z = blockIdx.z;
  const float* A = (z == 0) ? Xq : ((z == 1) ? Xk : Xv);
  const float* bias = (z == 0) ? bqp : ((z == 1) ? bkp : bvp);
  const bf16* W = Wc + (size_t)z * E_ * E_;
  bf16* out = dst + (size_t)z * B_ * T_ * D_ * H_;
  const int wm = (w >> 1) * 64;
  const int wn = (w & 1) * 64;

  const f32x4 zero4 = {0.f, 0.f, 0.f, 0.f};
  f32x4 acc[4][4];
#pragma unroll
  for (int i = 0; i < 4; ++i)
#pragma unroll
    for (int j = 0; j < 4; ++j) acc[i][j] = zero4;

  const int srow = w * 32 + (lane >> 2);
  const int scol = (lane & 3) * 8;
  const float* Ag = A + (size_t)(m0 + srow) * E_ + scol;
  const bf16* Wg = W + (size_t)(n0 + srow) * E_ + scol;
  const int sidx = w * 1024 + lane * 8;

  // prologue: stage kt=0 into buf0; prefetch A(kt=1) into regs
  float4 p0 = *(const float4*)(Ag);
  float4 p1 = *(const float4*)(Ag + 4);
  float4 p2 = *(const float4*)(Ag + (size_t)16 * E_);
  float4 p3 = *(const float4*)(Ag + (size_t)16 * E_ + 4);
  *(bhalf8*)(As + sidx) = cvt8(p0, p1);
  *(bhalf8*)(As + sidx + 512) = cvt8(p2, p3);
  gld_lds16(Wg, Bs + sidx);
  gld_lds16(Wg + (size_t)16 * E_, Bs + sidx + 512);
  p0 = *(const float4*)(Ag + 32);
  p1 = *(const float4*)(Ag + 36);
  p2 = *(const float4*)(Ag + (size_t)16 * E_ + 32);
  p3 = *(const float4*)(Ag + (size_t)16 * E_ + 36);
  __syncthreads();  // vmcnt0+lgkm0: buf0 ready

  for (int kt = 0; kt < 32; ++kt) {
    const int cur = (kt & 1) * 4096;
    bhalf8 af[4], bfr[4];
#pragma unroll
    for (int t2 = 0; t2 < 4; ++t2) {
      af[t2] = *(const bhalf8*)(As + cur + (wm + t2 * 16 + l15) * 32 + quad * 8);
      bfr[t2] = *(const bhalf8*)(Bs + cur + (wn + t2 * 16 + l15) * 32 + quad * 8);
    }
    if (kt < 31) {
      const int nxt = 4096 - cur;
      const int kc = (kt + 1) * 32;
      gld_lds16(Wg + kc, Bs + nxt + sidx);
      gld_lds16(Wg + (size_t)16 * E_ + kc, Bs + nxt + sidx + 512);
      *(bhalf8*)(As + nxt + sidx) = cvt8(p0, p1);
      *(bhalf8*)(As + nxt + sidx + 512) = cvt8(p2, p3);
      if (kt < 30) {
        const int kc2 = kc + 32;
        p0 = *(const float4*)(Ag + kc2);
        p1 = *(const float4*)(Ag + kc2 + 4);
        p2 = *(const float4*)(Ag + (size_t)16 * E_ + kc2);
        p3 = *(const float4*)(Ag + (size_t)16 * E_ + kc2 + 4);
      }
    }
#pragma unroll
    for (int mt = 0; mt < 4; ++mt)
#pragma unroll
      for (int nt = 0; nt < 4; ++nt)
        acc[mt][nt] = __builtin_amdgcn_mfma_f32_16x16x32_bf16(af[mt], bfr[nt], acc[mt][nt], 0, 0, 0);
    __syncthreads();  // drains staging vmcnt under/after MFMA; buf[nxt] ready
  }

#pragma unroll
  for (int mt = 0; mt < 4; ++mt) {
#pragma unroll
    for (int nt = 0; nt < 4; ++nt) {
      const int n = n0 + wn + nt * 16 + l15;
      const float bv = bias[n];
#pragma unroll
      for (int r = 0; r < 4; ++r) {
        const int m = m0 + wm + mt * 16 + quad * 4 + r;  // C row = quad*4+reg
        const float v = acc[mt][nt][r] + bv;
        const int bb = m >> 10, tq = m & 1023, hh = n >> 6, d = n & 63;
        out[(((size_t)bb * H_ + hh) * T_ + tq) * D_ + d] = __float2bfloat16(v);
      }
    }
  }
}

// ---------------------------------------------------------------------------
// Output projection (R5-proven 128x128 form, best measured). dbuf, single
// barrier, both operands via gld_lds. F32OUT: fp32 [M,N].
// ---------------------------------------------------------------------------
template <int SCATTER, int F32OUT>
__global__ __launch_bounds__(256) void gemm_bt(const bf16* __restrict__ A,
                                               const bf16* __restrict__ W,
                                               const float* __restrict__ bias,
                                               void* __restrict__ dst_) {
  __shared__ bf16 As[2 * 128 * 32];
  __shared__ bf16 Bs[2 * 128 * 32];
  const int tid = threadIdx.x;
  const int lane = tid & 63;
  const int w = tid >> 6;
  const int quad = lane >> 4;
  const int l15 = lane & 15;
  const int m0 = blockIdx.x * 128;
  const int n0 = blockIdx.y * 128;
  const int wm = (w >> 1) * 64;
  const int wn = (w & 1) * 64;

  const f32x4 zero4 = {0.f, 0.f, 0.f, 0.f};
  f32x4 acc[4][4];
#pragma unroll
  for (int i = 0; i < 4; ++i)
#pragma unroll
    for (int j = 0; j < 4; ++j) acc[i][j] = zero4;

  const int srow0 = w * 32 + (lane >> 2);
  const int scol = (lane & 3) * 8;
  const bf16* Ag = A + (size_t)(m0 + srow0) * E_ + scol;
  const bf16* Wg = W + (size_t)(n0 + srow0) * E_ + scol;
  const int sidx = w * 1024 + lane * 8;

  gld_lds16(Ag, As + sidx);
  gld_lds16(Ag + (size_t)16 * E_, As + sidx + 512);
  gld_lds16(Wg, Bs + sidx);
  gld_lds16(Wg + (size_t)16 * E_, Bs + sidx + 512);
  __syncthreads();

  for (int kt = 0; kt < 32; ++kt) {
    const int cur = (kt & 1) * 4096;
    bhalf8 af[4], bfr[4];
#pragma unroll
    for (int t = 0; t < 4; ++t) {
      af[t] = *(const bhalf8*)(As + cur + (wm + t * 16 + l15) * 32 + quad * 8);
      bfr[t] = *(const bhalf8*)(Bs + cur + (wn + t * 16 + l15) * 32 + quad * 8);
    }
    if (kt < 31) {
      const int nxt = 4096 - cur;
      const int kc = (kt + 1) * 32;
      gld_lds16(Ag + kc, As + nxt + sidx);
      gld_lds16(Ag + (size_t)16 * E_ + kc, As + nxt + sidx + 512);
      gld_lds16(Wg + kc, Bs + nxt + sidx);
      gld_lds16(Wg + (size_t)16 * E_ + kc, Bs + nxt + sidx + 512);
    }
#pragma unroll
    for (int mt = 0; mt < 4; ++mt)
#pragma unroll
      for (int nt = 0; nt < 4; ++nt)
        acc[mt][nt] = __builtin_amdgcn_mfma_f32_16x16x32_bf16(af[mt], bfr[nt], acc[mt][nt], 0, 0, 0);
    __syncthreads();
  }

#pragma unroll
  for (int mt = 0; mt < 4; ++mt) {
#pragma unroll
    for (int nt = 0; nt < 4; ++nt) {
      const int n = n0 + wn + nt * 16 + l15;
      const float bv = bias[n];
#pragma unroll
      for (int r = 0; r < 4; ++r) {
        const int m = m0 + wm + mt * 16 + quad * 4 + r;  // C row = quad*4+reg
        const float v = acc[mt][nt][r] + bv;
        if (SCATTER) {
          const int bb = m >> 10, t = m & 1023, hh = n >> 6, d = n & 63;
          ((bf16*)dst_)[(((size_t)bb * H_ + hh) * T_ + t) * D_ + d] = __float2bfloat16(v);
        } else if (F32OUT) {
          ((float*)dst_)[(size_t)m * E_ + n] = v;
        } else {
          ((bf16*)dst_)[(size_t)m * E_ + n] = __float2bfloat16(v);
        }
      }
    }
  }
}

// ---------------------------------------------------------------------------
// Flash attention, swapped-operand structure (verified R2 version, final:
// R3/R6 single-barrier and R12 paired-V/XCD-grid all regressed).
//   S^T = mfma(K, Q):  lane holds q = l15, kv = nt*16 + quad*4 + r
//   O^T = mfma(V^T, P): lane holds d = nt*16 + quad*4 + r, q = l15
//   - Ps: stride 64 + XOR swizzle (byte ^= (row&7)<<4) -> conflict-free.
//   - V tile prefetched into regs (T14), K frags hoisted to iteration top.
//   - softmax: tree-reduced max/sum, exp2 with log2e folded into bias.
//   - epilogue: O^T transposed through Ps then coalesced b128 stores.
// LDS 30208 B, 64 VGPR -> 4 blocks/CU.
// ---------------------------------------------------------------------------
__device__ __forceinline__ int ps_off(int row, int colbyte) {
  return row * 128 + (colbyte ^ ((row & 7) << 4));
}

__global__ __launch_bounds__(256, 4) void attn_kernel(const bf16* __restrict__ Q,
                                                      const bf16* __restrict__ K,
                                                      const bf16* __restrict__ V,
                                                      const float* __restrict__ db,
                                                      bf16* __restrict__ xout) {
  const int tid = threadIdx.x;
  const int lane = tid & 63;
  const int w = tid >> 6;
  const int quad = lane >> 4;
  const int l15 = lane & 15;
  const int bh = blockIdx.x;          // b*16 + h
  const int h = bh & 15;
  const int b = bh >> 4;
  const int q0 = blockIdx.y * 128;

  __shared__ bf16 Vt[64][72];                    // rotated V^T (9216 B)
  __shared__ __align__(16) bf16 Ps[4][32 * 64];  // swizzled P / O tiles (16384 B)
  __shared__ float dbs[1152];                    // bias slice (4608 B)

  const size_t base = (size_t)bh * T_ * D_;
  const bf16* Qp = Q + base;
  const bf16* Kp = K + base;
  const bf16* Vp = V + base;
  const float* dbh = db + h * NREL;

  for (int t = tid; t < 1151; t += 256) dbs[t] = dbh[q0 + t];

  const int qw = q0 + w * 32;
  bhalf8 aq[2][2];
#pragma unroll
  for (int mt = 0; mt < 2; ++mt)
#pragma unroll
    for (int ks = 0; ks < 2; ++ks)
      aq[mt][ks] = *(const bhalf8*)(Qp + (size_t)(qw + mt * 16 + l15) * D_ + ks * 32 + quad * 8);

  const f32x4 zero4 = {0.f, 0.f, 0.f, 0.f};
  f32x4 o[2][4];
#pragma unroll
  for (int mt = 0; mt < 2; ++mt)
#pragma unroll
    for (int nt = 0; nt < 4; ++nt) o[mt][nt] = zero4;
  float mrow[2] = {-1e30f, -1e30f};   // log2 units
  float lrow[2] = {0.f, 0.f};

  // V staging geometry: 2 chunks/thread, chunk = 8 consecutive d of one kv row
  const int vrow0 = tid >> 3;              // kv local (s=0)
  const int vc8 = (tid & 7) * 8;           // d chunk
  // prologue: prefetch V tile 0 into regs
  bhalf8 vreg[2];
  vreg[0] = *(const bhalf8*)(Vp + (size_t)vrow0 * D_ + vc8);
  vreg[1] = *(const bhalf8*)(Vp + (size_t)(vrow0 + 32) * D_ + vc8);

  char* const psw = (char*)&Ps[w][0];

  for (int it = 0; it < 16; ++it) {
    const int kb = it * 64;
    // K frags for this tile -- issue before the barrier region
    bhalf8 bk[4][2];
#pragma unroll
    for (int nt = 0; nt < 4; ++nt) {
      const bf16* kr = Kp + (size_t)(kb + nt * 16 + l15) * D_ + quad * 8;
      bk[nt][0] = *(const bhalf8*)kr;
      bk[nt][1] = *(const bhalf8*)(kr + 32);
    }

    __syncthreads();                  // previous iteration's Vt readers done
    // write prefetched V regs -> rotated Vt
#pragma unroll
    for (int s = 0; s < 2; ++s) {
      const int row = vrow0 + s * 32;
      const bf16* vp = (const bf16*)&vreg[s];
      const int kvp = (row + vc8) & 63;      // rotation: kv + (d&56)
#pragma unroll
      for (int j = 0; j < 8; ++j) Vt[vc8 + j][kvp] = vp[j];
    }
    __syncthreads();
    // prefetch next V tile (hidden under S/softmax/PV)
    if (it < 15) {
      const int kb2 = kb + 64;
      vreg[0] = *(const bhalf8*)(Vp + (size_t)(kb2 + vrow0) * D_ + vc8);
      vreg[1] = *(const bhalf8*)(Vp + (size_t)(kb2 + vrow0 + 32) * D_ + vc8);
    }

    // S^T = K Q^T
    f32x4 s4[2][4];
    __builtin_amdgcn_s_setprio(1);
#pragma unroll
    for (int nt = 0; nt < 4; ++nt) {
#pragma unroll
      for (int mt = 0; mt < 2; ++mt) {
        f32x4 a = zero4;
        a = __builtin_amdgcn_mfma_f32_16x16x32_bf16(bk[nt][0], aq[mt][0], a, 0, 0, 0);
        a = __builtin_amdgcn_mfma_f32_16x16x32_bf16(bk[nt][1], aq[mt][1], a, 0, 0, 0);
        s4[mt][nt] = a;
      }
    }
    __builtin_amdgcn_s_setprio(0);

    // softmax over kv (log2 domain): scale*log2e folded, bias pre-scaled
#pragma unroll
    for (int mt = 0; mt < 2; ++mt) {
      const int ib = w * 32 + mt * 16 + l15 + 1023 - kb;
      float mnt[4];
#pragma unroll
      for (int nt = 0; nt < 4; ++nt) {
#pragma unroll
        for (int r = 0; r < 4; ++r) {
          const float sv = s4[mt][nt][r] * 0.18033688011112042f + dbs[ib - nt * 16 - quad * 4 - r];
          s4[mt][nt][r] = sv;
        }
        mnt[nt] = fmaxf(fmaxf(s4[mt][nt][0], s4[mt][nt][1]),
                        fmaxf(s4[mt][nt][2], s4[mt][nt][3]));
      }
      float tmx = fmaxf(fmaxf(mnt[0], mnt[1]), fmaxf(mnt[2], mnt[3]));
      tmx = fmaxf(tmx, __shfl_xor(tmx, 16, 64));
      tmx = fmaxf(tmx, __shfl_xor(tmx, 32, 64));
      // defer-max (T13): 8 e-units ~= 11.5 log2-units
      if (!__all(tmx - mrow[mt] <= 11.0f)) {
        const float mnew = fmaxf(mrow[mt], tmx);
        const float alpha = __builtin_amdgcn_exp2f(mrow[mt] - mnew);
        mrow[mt] = mnew;
        lrow[mt] *= alpha;
#pragma unroll
        for (int nt = 0; nt < 4; ++nt) o[mt][nt] *= alpha;
      }
      const float mcur = mrow[mt];
      float psum[4];
#pragma unroll
      for (int nt = 0; nt < 4; ++nt) {
        float p0 = __builtin_amdgcn_exp2f(s4[mt][nt][0] - mcur);
        float p1 = __builtin_amdgcn_exp2f(s4[mt][nt][1] - mcur);
        float p2 = __builtin_amdgcn_exp2f(s4[mt][nt][2] - mcur);
        float p3 = __builtin_amdgcn_exp2f(s4[mt][nt][3] - mcur);
        s4[mt][nt][0] = p0; s4[mt][nt][1] = p1;
        s4[mt][nt][2] = p2; s4[mt][nt][3] = p3;
        psum[nt] = (p0 + p1) + (p2 + p3);
      }
      float sum = (psum[0] + psum[1]) + (psum[2] + psum[3]);
      sum += __shfl_xor(sum, 16, 64);
      sum += __shfl_xor(sum, 32, 64);
      lrow[mt] += sum;

      // P -> LDS (swizzled): lane holds 4 consecutive kv per (mt,nt)
#pragma unroll
      for (int nt = 0; nt < 4; ++nt) {
        alignas(8) bf16 t4[4];
#pragma unroll
        for (int r = 0; r < 4; ++r) t4[r] = __float2bfloat16(s4[mt][nt][r]);
        *(uint2*)(psw + ps_off(mt * 16 + l15, nt * 32 + quad * 8)) = *(const uint2*)t4;
      }
    }

    // P B-frags (swizzled read) + rotated-V^T A-frags -> O^T += V^T @ P
    bhalf8 pb[2][2];
#pragma unroll
    for (int mt = 0; mt < 2; ++mt)
#pragma unroll
      for (int ks = 0; ks < 2; ++ks)
        pb[mt][ks] = *(const bhalf8*)(psw + ps_off(mt * 16 + l15, ks * 64 + quad * 16));
    const int rot = (l15 >> 3);
    __builtin_amdgcn_s_setprio(1);
#pragma unroll
    for (int nt = 0; nt < 4; ++nt) {
      const int drow = nt * 16 + l15;
#pragma unroll
      for (int ks = 0; ks < 2; ++ks) {
        const int gp = (4 * ks + quad + 2 * nt + rot) & 7;
        const bhalf8 vb = *(const bhalf8*)&Vt[drow][gp * 8];
#pragma unroll
        for (int mt = 0; mt < 2; ++mt)
          o[mt][nt] = __builtin_amdgcn_mfma_f32_16x16x32_bf16(vb, pb[mt][ks], o[mt][nt], 0, 0, 0);
      }
    }
    __builtin_amdgcn_s_setprio(0);
  }

  // epilogue: O^T/l -> Ps (wave-private, swizzled) -> coalesced b128 stores
#pragma unroll
  for (int mt = 0; mt < 2; ++mt) {
    const float inv = 1.f / lrow[mt];
#pragma unroll
    for (int nt = 0; nt < 4; ++nt) {
      alignas(8) bf16 t4[4];
#pragma unroll
      for (int r = 0; r < 4; ++r) t4[r] = __float2bfloat16(o[mt][nt][r] * inv);
      *(uint2*)(psw + ps_off(mt * 16 + l15, nt * 32 + quad * 8)) = *(const uint2*)t4;
    }
  }
#pragma unroll
  for (int t = 0; t < 4; ++t) {
    const int idx = t * 64 + lane;     // 256 16B chunks: 32 rows x 8 chunks
    const int row = idx >> 3;
    const int c = idx & 7;
    const bhalf8 val = *(const bhalf8*)(psw + ps_off(row, c * 16));
    *(bhalf8*)&xout[((size_t)b * T_ + qw + row) * E_ + h * D_ + c * 8] = val;
  }
}

// ---------------------------------------------------------------------------
extern "C" void kernel_launch(void* const* d_in, const int* in_sizes, int n_in,
                              void* d_out, int out_size, void* d_ws, size_t ws_size,
                              hipStream_t stream) {
  const float* query = (const float*)d_in[0];
  const float* key_  = (const float*)d_in[1];
  const float* value = (const float*)d_in[2];
  const float* Wq = (const float*)d_in[3];
  const float* bq = (const float*)d_in[4];
  const float* Wk = (const float*)d_in[5];
  const float* bk = (const float*)d_in[6];
  const float* Wv = (const float*)d_in[7];
  const float* bv = (const float*)d_in[8];
  const float* Wo = (const float*)d_in[9];
  const float* bo = (const float*)d_in[10];
  const float* table = (const float*)d_in[11];
  const float* offset = (const float*)d_in[12];
  float* out = (float*)d_out;

  char* ws = (char*)d_ws;
  const size_t ME = (size_t)B_ * T_ * E_;   // 8.4M elems
  const size_t EE = (size_t)E_ * E_;        // 1M elems
  float* db = (float*)ws;                   // 131008 B, round to 131072
  bf16* wc  = (bf16*)(ws + 131072);         // converted Wq,Wk,Wv,Wo (4*EE)
  bf16* qb  = wc + 4 * EE;                  // fused QKV out: [3][B,H,T,D]
  bf16* kb  = qb + ME;
  bf16* vb2 = kb + ME;
  bf16* x2  = vb2 + ME;                     // attn out [B,T,E]

  dim3 bb(256, 1, 1);
  const int gEE = (int)(EE / 8 / 256);

  // weights cvt (z=0..3) + bias table precompute (z=4), one dispatch
  cvt_w4b<<<dim3(gEE, 5), bb, 0, stream>>>(Wq, Wk, Wv, Wo, wc, table, offset, db);

  // fused QKV: reg-staged A, dbuf, single barrier (best-measured form)
  gemm_qkv<<<dim3(64, 8, 3), bb, 0, stream>>>(query, key_, value, wc, bq, bk, bv, qb);

  attn_kernel<<<dim3(128, 8, 1), bb, 0, stream>>>(qb, kb, vb2, db, x2);

  gemm_bt<0, 1><<<dim3(64, 8, 1), bb, 0, stream>>>(x2, wc + 3 * EE, bo, out);
}